// Round 11
// baseline (4486.423 us; speedup 1.0000x reference)
//
#include <hip/hip_runtime.h>
#include <hip/hip_bf16.h>

#define NLAYERS 6
#define BB 8
#define TT 512
#define DMODEL 2048
#define DSTATE 128
#define DCONV 4
#define DINNER 4096
#define NTOK (BB*TT)              // 4096 tokens

typedef __bf16 bf16x8 __attribute__((ext_vector_type(8)));
typedef float floatx4 __attribute__((ext_vector_type(4)));
typedef unsigned short ushort8v __attribute__((ext_vector_type(8)));
typedef unsigned short ushort4v __attribute__((ext_vector_type(4)));

__device__ __forceinline__ float bf2f(unsigned short u) {
    return __uint_as_float(((unsigned)u) << 16);
}
__device__ __forceinline__ unsigned short f2bf(float f) {
    unsigned u = __float_as_uint(f);
    unsigned r = u + 0x7FFFu + ((u >> 16) & 1u);   // round-nearest-even
    return (unsigned short)(r >> 16);
}
__device__ __forceinline__ float siluf(float x) { return x / (1.f + __expf(-x)); }
__device__ __forceinline__ float softplusf(float x) {
    return fmaxf(x, 0.f) + log1pf(__expf(-fabsf(x)));
}

__device__ __forceinline__ void gload16(const void* g, void* l) {
    __builtin_amdgcn_global_load_lds(
        (const __attribute__((address_space(1))) void*)g,
        (__attribute__((address_space(3))) void*)l, 16, 0, 0);
}

#define BARR __builtin_amdgcn_s_barrier()
#define SCHB __builtin_amdgcn_sched_barrier(0)
#define PRIO1 __builtin_amdgcn_s_setprio(1)
#define PRIO0 __builtin_amdgcn_s_setprio(0)

// ---------------- fp32 -> bf16 weight conversion ----------------
__global__ __launch_bounds__(256) void cvt_kernel(const float* __restrict__ s,
                                                  unsigned short* __restrict__ d, int n) {
    int i = (blockIdx.x * blockDim.x + threadIdx.x) * 4;
    if (i < n) {
        float4 v = *(const float4*)(s + i);
        ushort4v o = {f2bf(v.x), f2bf(v.y), f2bf(v.z), f2bf(v.w)};
        *(ushort4v*)(d + i) = o;
    }
}

// ---------------- fp32 -> fp8 e4m3 (scaled) conversion ----------------
__global__ __launch_bounds__(256) void cvt8_kernel(const float* __restrict__ s,
                                                   unsigned char* __restrict__ d,
                                                   float scale) {
    int i = (blockIdx.x * blockDim.x + threadIdx.x) * 8;
    float4 v0 = *(const float4*)(s + i);
    float4 v1 = *(const float4*)(s + i + 4);
    int lo = __builtin_amdgcn_cvt_pk_fp8_f32(v0.x * scale, v0.y * scale, 0, false);
    lo = __builtin_amdgcn_cvt_pk_fp8_f32(v0.z * scale, v0.w * scale, lo, true);
    int hi = __builtin_amdgcn_cvt_pk_fp8_f32(v1.x * scale, v1.y * scale, 0, false);
    hi = __builtin_amdgcn_cvt_pk_fp8_f32(v1.z * scale, v1.w * scale, hi, true);
    int2 o = {lo, hi};
    *(int2*)(d + i) = o;
}

// ---------------- LayerNorm: fp32 in -> bf16 out ----------------
__global__ __launch_bounds__(256) void ln_kernel(const float* __restrict__ x,
                                                 const float* __restrict__ g,
                                                 const float* __restrict__ b,
                                                 unsigned short* __restrict__ out) {
    const int row = blockIdx.x;
    const float* xr = x + (long)row * DMODEL;
    const int base = threadIdx.x * 8;
    float4 v0 = *(const float4*)(xr + base);
    float4 v1 = *(const float4*)(xr + base + 4);
    float vv[8] = {v0.x, v0.y, v0.z, v0.w, v1.x, v1.y, v1.z, v1.w};
    float s = 0.f, s2 = 0.f;
#pragma unroll
    for (int j = 0; j < 8; j++) { s += vv[j]; s2 += vv[j] * vv[j]; }
#pragma unroll
    for (int off = 32; off >= 1; off >>= 1) {
        s += __shfl_xor(s, off);
        s2 += __shfl_xor(s2, off);
    }
    __shared__ float red[8];
    int wave = threadIdx.x >> 6, lane = threadIdx.x & 63;
    if (lane == 0) { red[wave] = s; red[4 + wave] = s2; }
    __syncthreads();
    s = red[0] + red[1] + red[2] + red[3];
    s2 = red[4] + red[5] + red[6] + red[7];
    float mu = s * (1.f / DMODEL);
    float var = s2 * (1.f / DMODEL) - mu * mu;
    float rs = rsqrtf(var + 1e-5f);
    ushort8v ov;
#pragma unroll
    for (int j = 0; j < 8; j++)
        ov[j] = f2bf((vv[j] - mu) * rs * g[base + j] + b[base + j]);
    *(ushort8v*)&out[(long)row * DMODEL + base] = ov;
}

// ---------------- combine: hout = p0 + p1 + h ----------------
__global__ __launch_bounds__(256) void combine3_kernel(const float* __restrict__ p0,
                                                       const float* __restrict__ p1,
                                                       const float* __restrict__ h,
                                                       float* __restrict__ out) {
    long i = (long)(blockIdx.x * blockDim.x + threadIdx.x) * 4;
    float4 a = *(const float4*)(p0 + i);
    float4 b = *(const float4*)(p1 + i);
    float4 c = *(const float4*)(h + i);
    float4 o = {a.x+b.x+c.x, a.y+b.y+c.y, a.z+b.z+c.z, a.w+b.w+c.w};
    *(float4*)(out + i) = o;
}

// ============ 256x256 bf16 GEMM, BK=32, 3-buffer LDS (R7 schedule): C = A*B^T ============
// 512 thr, 8 waves: wm=w>>2 (M 128-band), wn=w&3 (N 64-band); acc[8][4].
// LDS buffer = A 16KB + B 16KB, x3 = 96KB. 2 matrix rows per 128B LDS row (64B K-slices);
// stored 16B slot = ((r&1)*4+chunk) ^ (ldsrow&7) (R9-refchecked map family).
// Per tile: vmcnt(4); barrier; STAGE(t+2, 4 gload16); 12 ds_read_b128; lgkm(4) ->
// MFMA mi0-3 (af4-7 in flight); lgkm(0) -> MFMA mi4-7. EPI 0: bf16 store. EPI 3: fp32 K-part.
template <int EPI>
__global__ __launch_bounds__(512, 1) void gemm_sq(const unsigned short* __restrict__ A,
                                                  const unsigned short* __restrict__ B,
                                                  int Kstr, int RY, int KT, int ldc,
                                                  unsigned short* __restrict__ Cbf,
                                                  float* __restrict__ Cf0,
                                                  float* __restrict__ Cf1) {
    __shared__ __align__(16) char lds[3 * 32768];
    const int tid = threadIdx.x;
    const int w = tid >> 6, lane = tid & 63;
    const int wm = w >> 2, wn = w & 3;

    const int xcd = blockIdx.x & 7;
    const int l = blockIdx.x >> 3;
    const int by = xcd * RY + (l % RY);
    const int rest = l / RY;
    int bx = 0, kpart = 0;
    if constexpr (EPI == 3) { bx = rest & 7; kpart = rest >> 3; }
    else { bx = rest; }
    const long rowBase = (long)by * 256;
    const long colBase = (long)bx * 256;
    const long K0b = (long)kpart * KT * 64;

    // frag-read constants
    const int slotRD = ((((lane & 1) << 2) | (lane >> 4)) ^ ((lane >> 1) & 7)) * 16;
    const char* rdA = lds + wm * 8192 + ((lane >> 1) & 7) * 128 + slotRD;
    const char* rdB = lds + 16384 + wn * 4096 + ((lane >> 1) & 7) * 128 + slotRD;

    // staging source (inverse-swizzled global addr, linear LDS dest)
    const int t8 = tid >> 3;
    const int ch3 = (tid & 7) ^ (t8 & 7);
    const int srow = 2 * t8 + (ch3 >> 2);
    const int coff = (ch3 & 3) * 16;
    const size_t Kb2 = (size_t)Kstr * 2;
    const char* pA1 = (const char*)A + (rowBase + srow) * Kb2 + coff + K0b;
    const char* pA2 = (const char*)A + (rowBase + 128 + srow) * Kb2 + coff + K0b;
    const char* pB1 = (const char*)B + (colBase + srow) * Kb2 + coff + K0b;
    const char* pB2 = (const char*)B + (colBase + 128 + srow) * Kb2 + coff + K0b;
    const long wb = (long)w * 1024;

    floatx4 acc[8][4];
#pragma unroll
    for (int m = 0; m < 8; m++)
#pragma unroll
        for (int n = 0; n < 4; n++) acc[m][n] = floatx4{0.f, 0.f, 0.f, 0.f};

#define STG(BUF, OFF) do { \
    gload16(pA1 + (OFF), lds + (BUF)*32768 + wb); \
    gload16(pA2 + (OFF), lds + (BUF)*32768 + 8192 + wb); \
    gload16(pB1 + (OFF), lds + (BUF)*32768 + 16384 + wb); \
    gload16(pB2 + (OFF), lds + (BUF)*32768 + 24576 + wb); } while(0)

    STG(0, 0);
    STG(1, 64);

    for (int t = 0; t < KT; t++) {
        const long bo = (long)(t % 3) * 32768;
        const int bufS = (t + 2) % 3;
        const size_t off2 = (size_t)((t + 2 < KT) ? (t + 2) : (KT - 1)) * 64;
        asm volatile("s_waitcnt vmcnt(4)");
        BARR;
        STG(bufS, off2);
        bf16x8 bfr[4], af[8];
#pragma unroll
        for (int n = 0; n < 4; n++) bfr[n] = *(const bf16x8*)(rdB + bo + n * 1024);
#pragma unroll
        for (int m = 0; m < 8; m++) af[m] = *(const bf16x8*)(rdA + bo + m * 1024);
        asm volatile("s_waitcnt lgkmcnt(4)"); SCHB;
        PRIO1;
#pragma unroll
        for (int m = 0; m < 4; m++)
#pragma unroll
            for (int n = 0; n < 4; n++)
                acc[m][n] = __builtin_amdgcn_mfma_f32_16x16x32_bf16(bfr[n], af[m], acc[m][n], 0, 0, 0);
        PRIO0;
        asm volatile("s_waitcnt lgkmcnt(0)"); SCHB;
        PRIO1;
#pragma unroll
        for (int m = 4; m < 8; m++)
#pragma unroll
            for (int n = 0; n < 4; n++)
                acc[m][n] = __builtin_amdgcn_mfma_f32_16x16x32_bf16(bfr[n], af[m], acc[m][n], 0, 0, 0);
        PRIO0;
    }
#undef STG

    // epilogue (M-row = lane&15, N-col = (lane>>4)*4 + reg)
    const int lrow = lane & 15, cg = (lane >> 4) * 4;
    if constexpr (EPI == 0) {
#pragma unroll
        for (int mi = 0; mi < 8; mi++)
#pragma unroll
            for (int n = 0; n < 4; n++) {
                long row = rowBase + wm * 128 + mi * 16 + lrow;
                long col = colBase + wn * 64 + n * 16 + cg;
                ushort4v o = {f2bf(acc[mi][n][0]), f2bf(acc[mi][n][1]),
                              f2bf(acc[mi][n][2]), f2bf(acc[mi][n][3])};
                *(ushort4v*)&Cbf[row * ldc + col] = o;
            }
    } else {   // EPI == 3: fp32 K-split partial
        float* op = (kpart == 0) ? Cf0 : Cf1;
#pragma unroll
        for (int mi = 0; mi < 8; mi++)
#pragma unroll
            for (int n = 0; n < 4; n++) {
                long row = rowBase + wm * 128 + mi * 16 + lrow;
                long col = colBase + wn * 64 + n * 16 + cg;
                *(floatx4*)&op[row * ldc + col] = acc[mi][n];
            }
    }
}

// ============ 256x256 fp8 W_dt GEMM, BK=64 bytes, 3-buffer (same maps) ============
// A8 = xc*4, B8 = W_dt*64; acc/256 in epilogue. KT=64 tiles; 2 ksteps of
// mfma_f32_16x16x32_fp8_fp8 per tile. Grid 256 (16by x 16bx).
__global__ __launch_bounds__(512, 1) void gemm_dt8(const unsigned char* __restrict__ A8,
                                                   const unsigned char* __restrict__ B8,
                                                   const float* __restrict__ bias,
                                                   float* __restrict__ dmean) {
    __shared__ __align__(16) char lds[3 * 32768];
    const int tid = threadIdx.x;
    const int w = tid >> 6, lane = tid & 63;
    const int wm = w >> 2, wn = w & 3;

    const int xcd = blockIdx.x & 7;
    const int l = blockIdx.x >> 3;
    const int by = xcd * 2 + (l & 1);
    const int bx = l >> 1;             // 0..15
    const long rowBase = (long)by * 256;
    const long colBase = (long)bx * 256;

    // frag-read constants per kstep s: chunk = s*2+(lane>>5), inner 8B = ((lane>>4)&1)*8
    int cbs[2];
#pragma unroll
    for (int s = 0; s < 2; s++)
        cbs[s] = (((((lane & 1) << 2) | (s * 2 + (lane >> 5))) ^ ((lane >> 1) & 7)) * 16)
                 + ((lane >> 4) & 1) * 8;
    const char* rdA = lds + wm * 8192 + ((lane >> 1) & 7) * 128;
    const char* rdB = lds + 16384 + wn * 4096 + ((lane >> 1) & 7) * 128;

    const int t8 = tid >> 3;
    const int ch3 = (tid & 7) ^ (t8 & 7);
    const int srow = 2 * t8 + (ch3 >> 2);
    const int coff = (ch3 & 3) * 16;
    const char* pA1 = (const char*)A8 + (rowBase + srow) * (size_t)DINNER + coff;
    const char* pA2 = (const char*)A8 + (rowBase + 128 + srow) * (size_t)DINNER + coff;
    const char* pB1 = (const char*)B8 + (colBase + srow) * (size_t)DINNER + coff;
    const char* pB2 = (const char*)B8 + (colBase + 128 + srow) * (size_t)DINNER + coff;
    const long wb = (long)w * 1024;

    floatx4 acc[8][4];
#pragma unroll
    for (int m = 0; m < 8; m++)
#pragma unroll
        for (int n = 0; n < 4; n++) acc[m][n] = floatx4{0.f, 0.f, 0.f, 0.f};

#define STG8(BUF, OFF) do { \
    gload16(pA1 + (OFF), lds + (BUF)*32768 + wb); \
    gload16(pA2 + (OFF), lds + (BUF)*32768 + 8192 + wb); \
    gload16(pB1 + (OFF), lds + (BUF)*32768 + 16384 + wb); \
    gload16(pB2 + (OFF), lds + (BUF)*32768 + 24576 + wb); } while(0)

    STG8(0, 0);
    STG8(1, 64);

    const int KT = DINNER / 64;   // 64 tiles
    for (int t = 0; t < KT; t++) {
        const long bo = (long)(t % 3) * 32768;
        const int bufS = (t + 2) % 3;
        const size_t off2 = (size_t)((t + 2 < KT) ? (t + 2) : (KT - 1)) * 64;
        asm volatile("s_waitcnt vmcnt(4)");
        BARR;
        STG8(bufS, off2);
        long b0[4], a0[8], b1[4], a1[8];
#pragma unroll
        for (int n = 0; n < 4; n++) b0[n] = *(const long*)(rdB + bo + n * 1024 + cbs[0]);
#pragma unroll
        for (int m = 0; m < 8; m++) a0[m] = *(const long*)(rdA + bo + m * 1024 + cbs[0]);
#pragma unroll
        for (int n = 0; n < 4; n++) b1[n] = *(const long*)(rdB + bo + n * 1024 + cbs[1]);
#pragma unroll
        for (int m = 0; m < 8; m++) a1[m] = *(const long*)(rdA + bo + m * 1024 + cbs[1]);
        asm volatile("s_waitcnt lgkmcnt(12)"); SCHB;
        PRIO1;
#pragma unroll
        for (int m = 0; m < 8; m++)
#pragma unroll
            for (int n = 0; n < 4; n++)
                acc[m][n] = __builtin_amdgcn_mfma_f32_16x16x32_fp8_fp8(b0[n], a0[m], acc[m][n], 0, 0, 0);
        PRIO0;
        asm volatile("s_waitcnt lgkmcnt(0)"); SCHB;
        PRIO1;
#pragma unroll
        for (int m = 0; m < 8; m++)
#pragma unroll
            for (int n = 0; n < 4; n++)
                acc[m][n] = __builtin_amdgcn_mfma_f32_16x16x32_fp8_fp8(b1[n], a1[m], acc[m][n], 0, 0, 0);
        PRIO0;
    }
#undef STG8

    // epilogue: softplus(acc/256 + b_dt) row-sum -> dmean atomics
    const int lrow = lane & 15, cg = (lane >> 4) * 4;
    const float SC = 1.f / 256.f;
    float4 bi[4];
#pragma unroll
    for (int n = 0; n < 4; n++)
        bi[n] = *(const float4*)&bias[colBase + wn * 64 + n * 16 + cg];
#pragma unroll
    for (int mi = 0; mi < 8; mi++) {
        float s = 0.f;
#pragma unroll
        for (int n = 0; n < 4; n++) {
            s += softplusf(acc[mi][n][0] * SC + bi[n].x);
            s += softplusf(acc[mi][n][1] * SC + bi[n].y);
            s += softplusf(acc[mi][n][2] * SC + bi[n].z);
            s += softplusf(acc[mi][n][3] * SC + bi[n].w);
        }
        s += __shfl_xor(s, 16);
        s += __shfl_xor(s, 32);
        if ((lane >> 4) == 0)
            atomicAdd(&dmean[rowBase + wm * 128 + mi * 16 + lrow], s);
    }
}

// ============ 128x256 bf16 W_xp GEMM (R10 structure, K-split x4 -> bcp) ============
#define BUFSZ 49152
__global__ __launch_bounds__(512, 1) void gemm_xp(const unsigned short* __restrict__ A,
                                                  const unsigned short* __restrict__ B,
                                                  float* __restrict__ bcout) {
    __shared__ __align__(16) char lds[3 * BUFSZ];
    const int tid = threadIdx.x;
    const int w = tid >> 6, lane = tid & 63;
    const int wm = w >> 2, wn = w & 3;
    const int lrow = lane & 15;

    const int xcd = blockIdx.x & 7;
    const int l = blockIdx.x >> 3;
    const int by = xcd * 4 + (l % 4);
    const int kpart = l / 4;
    const long rowBase = (long)by * 128;
    const long K0b = (long)kpart * 16 * 128;

    const int cb0 = (((lane >> 4))     ^ (lane & 7)) * 16;
    const int cb1 = (((lane >> 4) | 4) ^ (lane & 7)) * 16;
    const char* rdA = lds + (wm * 64 + lrow) * 128;
    const char* rdB = lds + 16384 + (wn * 64 + lrow) * 128;

    const int rsub = lane >> 3;
    const int csrc = (lane & 7) ^ (lane >> 3);
    char* ldsw = lds + w * 1024;
    const size_t Kb = (size_t)DINNER;
    const char* pA[2];
#pragma unroll
    for (int u = 0; u < 2; u++)
        pA[u] = (const char*)(A + (rowBase + u * 64 + w * 8 + rsub) * Kb) + csrc * 16 + K0b;
    const char* pB[4];
#pragma unroll
    for (int u = 0; u < 4; u++)
        pB[u] = (const char*)(B + ((long)u * 64 + w * 8 + rsub) * Kb) + csrc * 16 + K0b;

    floatx4 acc[4][4];
#pragma unroll
    for (int m = 0; m < 4; m++)
#pragma unroll
        for (int n = 0; n < 4; n++) acc[m][n] = floatx4{0.f, 0.f, 0.f, 0.f};
    bf16x8 af0[4], af1[4], bf0[4], bf1[4];

#define STGX(BUF, OFF) do { \
    _Pragma("unroll") for (int u_ = 0; u_ < 2; u_++) \
        gload16(pA[u_] + (OFF), ldsw + (BUF)*BUFSZ + u_*8192); \
    _Pragma("unroll") for (int u_ = 0; u_ < 4; u_++) \
        gload16(pB[u_] + (OFF), ldsw + (BUF)*BUFSZ + 16384 + u_*8192); } while(0)

#define MFMAX(AF, BF) do { _Pragma("unroll") \
  for (int m_ = 0; m_ < 4; m_++) { _Pragma("unroll") \
    for (int n_ = 0; n_ < 4; n_++) \
      acc[m_][n_] = __builtin_amdgcn_mfma_f32_16x16x32_bf16(BF[n_], AF[m_], acc[m_][n_], 0,0,0); } } while(0)

    STGX(0, 0);
    STGX(1, 128);

    const int KT = 16;
    for (int t = 0; t < KT; t++) {
        const int buf = t % 3;
        const int bufS = (t + 2) % 3;
        const long bufOff = (long)buf * BUFSZ;
        const size_t off2 = (size_t)((t + 2 < KT) ? (t + 2) : (KT - 1)) * 128;
        asm volatile("s_waitcnt vmcnt(6)");
        BARR;
        STGX(bufS, off2);
#pragma unroll
        for (int m_ = 0; m_ < 4; m_++)
            af0[m_] = *(const bf16x8*)(rdA + bufOff + m_ * 2048 + cb0);
#pragma unroll
        for (int n_ = 0; n_ < 4; n_++)
            bf0[n_] = *(const bf16x8*)(rdB + bufOff + n_ * 2048 + cb0);
#pragma unroll
        for (int m_ = 0; m_ < 4; m_++)
            af1[m_] = *(const bf16x8*)(rdA + bufOff + m_ * 2048 + cb1);
#pragma unroll
        for (int n_ = 0; n_ < 4; n_++)
            bf1[n_] = *(const bf16x8*)(rdB + bufOff + n_ * 2048 + cb1);
        asm volatile("s_waitcnt lgkmcnt(8)"); SCHB;
        PRIO1; MFMAX(af0, bf0); PRIO0;
        asm volatile("s_waitcnt lgkmcnt(0)"); SCHB;
        PRIO1; MFMAX(af1, bf1); PRIO0;
    }
#undef STGX
#undef MFMAX

    const int cg = (lane >> 4) * 4;
    float* op = bcout + (long)kpart * NTOK * 256;
#pragma unroll
    for (int mi = 0; mi < 4; mi++)
#pragma unroll
        for (int n = 0; n < 4; n++) {
            long row = rowBase + wm * 64 + mi * 16 + lrow;
            long col = wn * 64 + n * 16 + cg;
            *(floatx4*)&op[row * 256 + col] = acc[mi][n];
        }
}

// ---------------- causal depthwise conv1d + bias + silu (bf16 + scaled fp8 out) ----------------
__global__ __launch_bounds__(256) void conv_silu_kernel(const unsigned short* __restrict__ xr,
                                                        const float* __restrict__ w,
                                                        const float* __restrict__ cb,
                                                        unsigned short* __restrict__ xc,
                                                        unsigned char* __restrict__ xc8) {
    int idx = blockIdx.x * blockDim.x + threadIdx.x;   // NTOK * 512
    int d0 = (idx & 511) * 8;
    int bt = idx >> 9;
    int t = bt & (TT - 1);
    float acc[8];
#pragma unroll
    for (int j = 0; j < 8; j++) acc[j] = cb[d0 + j];
#pragma unroll
    for (int k = 0; k < DCONV; k++) {
        int ts = t - (DCONV - 1) + k;
        if (ts < 0) continue;
        ushort8v v = *(const ushort8v*)&xr[(long)(bt - (DCONV - 1) + k) * (2 * DINNER) + d0];
#pragma unroll
        for (int j = 0; j < 8; j++) acc[j] += bf2f(v[j]) * w[(d0 + j) * DCONV + k];
    }
    float sv[8];
    ushort8v ov;
#pragma unroll
    for (int j = 0; j < 8; j++) { sv[j] = siluf(acc[j]); ov[j] = f2bf(sv[j]); }
    *(ushort8v*)&xc[(long)bt * DINNER + d0] = ov;
    int lo = __builtin_amdgcn_cvt_pk_fp8_f32(sv[0] * 4.f, sv[1] * 4.f, 0, false);
    lo = __builtin_amdgcn_cvt_pk_fp8_f32(sv[2] * 4.f, sv[3] * 4.f, lo, true);
    int hi = __builtin_amdgcn_cvt_pk_fp8_f32(sv[4] * 4.f, sv[5] * 4.f, 0, false);
    hi = __builtin_amdgcn_cvt_pk_fp8_f32(sv[6] * 4.f, sv[7] * 4.f, hi, true);
    int2 o8 = {lo, hi};
    *(int2*)&xc8[(long)bt * DINNER + d0] = o8;
}

// ---------------- bc = sum of 4 K-split partials ----------------
__global__ __launch_bounds__(256) void bcsum_kernel(const float* __restrict__ bcp,
                                                    float* __restrict__ bc) {
    long i = (long)(blockIdx.x * blockDim.x + threadIdx.x) * 4;
    const long S = (long)NTOK * 256;
    float4 a = *(const float4*)(bcp + i);
    float4 b = *(const float4*)(bcp + S + i);
    float4 c = *(const float4*)(bcp + 2*S + i);
    float4 d = *(const float4*)(bcp + 3*S + i);
    float4 o = {a.x+b.x+c.x+d.x, a.y+b.y+c.y+d.y, a.z+b.z+c.z+d.z, a.w+b.w+c.w+d.w};
    *(float4*)(bc + i) = o;
}

// ---------------- sequential selective-scan (1 wave per batch) ----------------
__global__ void scan_kernel(const float* __restrict__ dmean, const float* __restrict__ bcmat,
                            const float* __restrict__ A_log, float* __restrict__ ys) {
    int b = blockIdx.x, lane = threadIdx.x;   // 64 lanes, 2 states each
    float A0 = -expf(A_log[lane]);
    float A1 = -expf(A_log[lane + 64]);
    float h0 = 0.f, h1 = 0.f;
    const float inv = 1.f / (float)DINNER;
    const float* rowp = bcmat + (long)b * TT * (2 * DSTATE);
    const float* dmp = dmean + b * TT;
    float B0 = rowp[lane], B1 = rowp[64 + lane];
    float C0 = rowp[128 + lane], C1 = rowp[192 + lane];
    float DM = dmp[0];
    for (int t = 0; t < TT; t++) {
        float nB0 = 0.f, nB1 = 0.f, nC0 = 0.f, nC1 = 0.f, nDM = 0.f;
        if (t + 1 < TT) {
            const float* nx = rowp + (long)(t + 1) * 256;
            nB0 = nx[lane]; nB1 = nx[64 + lane];
            nC0 = nx[128 + lane]; nC1 = nx[192 + lane];
            nDM = dmp[t + 1];
        }
        float dm = DM * inv;
        h0 = h0 * __expf(dm * A0) + B0;
        h1 = h1 * __expf(dm * A1) + B1;
        float v = h0 * C0 + h1 * C1;
#pragma unroll
        for (int off = 32; off >= 1; off >>= 1) v += __shfl_xor(v, off);
        if (lane == 0) ys[b * TT + t] = v;
        B0 = nB0; B1 = nB1; C0 = nC0; C1 = nC1; DM = nDM;
    }
}

// ---------------- y = (ys + D_skip*xc) * silu(res) ----------------
__global__ __launch_bounds__(256) void ycomb_kernel(const float* __restrict__ ys,
                                                    const unsigned short* __restrict__ xc,
                                                    const unsigned short* __restrict__ xr,
                                                    const float* __restrict__ dskip,
                                                    unsigned short* __restrict__ yc) {
    int idx = blockIdx.x * blockDim.x + threadIdx.x;
    int d0 = (idx & 511) * 8;
    int bt = idx >> 9;
    float y = ys[bt];
    ushort8v xcv = *(const ushort8v*)&xc[(long)bt * DINNER + d0];
    ushort8v rv = *(const ushort8v*)&xr[(long)bt * (2 * DINNER) + DINNER + d0];
    ushort8v ov;
#pragma unroll
    for (int j = 0; j < 8; j++) {
        float val = (y + dskip[d0 + j] * bf2f(xcv[j])) * siluf(bf2f(rv[j]));
        ov[j] = f2bf(val);
    }
    *(ushort8v*)&yc[(long)bt * DINNER + d0] = ov;
}

extern "C" void kernel_launch(void* const* d_in, const int* in_sizes, int n_in,
                              void* d_out, int out_size, void* d_ws, size_t ws_size,
                              hipStream_t stream) {
    const float* x      = (const float*)d_in[0];
    const float* ln_g   = (const float*)d_in[1];
    const float* ln_b   = (const float*)d_in[2];
    const float* W_in   = (const float*)d_in[3];
    const float* conv_w = (const float*)d_in[4];
    const float* conv_b = (const float*)d_in[5];
    const float* W_xp   = (const float*)d_in[6];
    const float* W_dt   = (const float*)d_in[7];
    const float* b_dt   = (const float*)d_in[8];
    const float* A_log  = (const float*)d_in[9];
    const float* D_skip = (const float*)d_in[10];
    const float* W_out  = (const float*)d_in[11];
    float* out = (float*)d_out;

    // workspace carve
    char* ws = (char*)d_ws;
    const size_t nWin  = (size_t)2 * DINNER * DMODEL;
    const size_t nWdt  = (size_t)DINNER * DINNER;
    const size_t nWxp  = (size_t)2 * DSTATE * DINNER;
    const size_t nWout = (size_t)DMODEL * DINNER;

    unsigned short* wb_in  = (unsigned short*)ws; ws += nWin * 2;
    unsigned char*  wb_dt8 = (unsigned char*)ws;  ws += nWdt;
    unsigned short* wb_xp  = (unsigned short*)ws; ws += nWxp * 2;
    unsigned short* wb_out = (unsigned short*)ws; ws += nWout * 2;
    unsigned short* xn = (unsigned short*)ws; ws += (size_t)NTOK * DMODEL * 2;
    unsigned short* xr = (unsigned short*)ws; ws += (size_t)NTOK * 2 * DINNER * 2;
    unsigned short* xc = (unsigned short*)ws; ws += (size_t)NTOK * DINNER * 2;
    unsigned char*  xc8 = (unsigned char*)ws; ws += (size_t)NTOK * DINNER;
    unsigned short* yc = (unsigned short*)ws; ws += (size_t)NTOK * DINNER * 2;
    float* bc    = (float*)ws; ws += (size_t)NTOK * 2 * DSTATE * 4;
    float* bcp   = (float*)ws; ws += (size_t)4 * NTOK * 2 * DSTATE * 4;
    float* dmean = (float*)ws; ws += (size_t)NTOK * 4;
    float* ysb   = (float*)ws; ws += (size_t)NTOK * 4;
    float* h0    = (float*)ws; ws += (size_t)NTOK * DMODEL * 4;
    float* h1    = (float*)ws; ws += (size_t)NTOK * DMODEL * 4;
    float* p0    = (float*)ws; ws += (size_t)NTOK * DMODEL * 4;
    float* p1    = (float*)ws; ws += (size_t)NTOK * DMODEL * 4;

    const float* hin = x;
    for (int lay = 0; lay < NLAYERS; lay++) {
        cvt_kernel<<<(int)(nWin / 1024), 256, 0, stream>>>(W_in + (size_t)lay * nWin, wb_in, (int)nWin);
        cvt8_kernel<<<(int)(nWdt / 2048), 256, 0, stream>>>(W_dt + (size_t)lay * nWdt, wb_dt8, 64.f);
        cvt_kernel<<<(int)(nWxp / 1024), 256, 0, stream>>>(W_xp + (size_t)lay * nWxp, wb_xp, (int)nWxp);
        cvt_kernel<<<(int)(nWout / 1024), 256, 0, stream>>>(W_out + (size_t)lay * nWout, wb_out, (int)nWout);

        hipMemsetAsync(dmean, 0, (size_t)NTOK * 4, stream);

        // 1) LayerNorm
        ln_kernel<<<NTOK, 256, 0, stream>>>(hin, ln_g + lay * DMODEL, ln_b + lay * DMODEL, xn);

        // 2) x_and_res = xn @ W_in^T  [4096 x 8192], K=2048, 256² tile: grid 16y x 32x = 512
        gemm_sq<0><<<512, 512, 0, stream>>>(xn, wb_in, DMODEL, 2, 64, 2 * DINNER,
                                            xr, nullptr, nullptr);

        // 3) causal depthwise conv + silu (bf16 + fp8 outputs)
        conv_silu_kernel<<<NTOK * 512 / 256, 256, 0, stream>>>(
            xr, conv_w + (size_t)lay * DINNER * DCONV, conv_b + (size_t)lay * DINNER, xc, xc8);

        // 4a) W_dt fp8 GEMM [4096 x 4096], K=4096, 256² tile: grid 16y x 16x = 256
        gemm_dt8<<<256, 512, 0, stream>>>(xc8, wb_dt8, b_dt + (size_t)lay * DINNER, dmean);

        // 4b) W_xp bf16 GEMM [4096 x 256], K-split x4 (KT=16): grid 32y x 4k = 128
        gemm_xp<<<128, 512, 0, stream>>>(xc, wb_xp, bcp);

        // 4c) bc = sum of partials
        bcsum_kernel<<<(NTOK * 256 / 4) / 256, 256, 0, stream>>>(bcp, bc);

        // 5) sequential scan -> ys
        scan_kernel<<<BB, 64, 0, stream>>>(dmean, bc, A_log + (size_t)lay * DSTATE, ysb);

        // 6) y = (ys + D_skip*xc) * silu(res)
        ycomb_kernel<<<NTOK * 512 / 256, 256, 0, stream>>>(
            ysb, xc, xr, D_skip + (size_t)lay * DINNER, yc);

        // 7) W_out partials [4096 x 2048], K-split x2 (KT=64), 256² tile: grid 16y x 8x x 2k = 256
        gemm_sq<3><<<256, 512, 0, stream>>>(yc, wb_out, DINNER, 2, 64, DMODEL,
                                            nullptr, p0, p1);

        // 8) hout = p0 + p1 + hin (residual); last layer writes d_out
        float* hcur = (lay == NLAYERS - 1) ? out : ((lay & 1) ? h1 : h0);
        combine3_kernel<<<(NTOK * DMODEL / 4) / 256, 256, 0, stream>>>(p0, p1, hin, hcur);
        hin = hcur;
    }
    (void)in_sizes; (void)n_in; (void)out_size; (void)ws_size;
}

// Round 12
// 3911.551 us; speedup vs baseline: 1.1470x; 1.1470x over previous
//
#include <hip/hip_runtime.h>
#include <hip/hip_bf16.h>

#define NLAYERS 6
#define BB 8
#define TT 512
#define DMODEL 2048
#define DSTATE 128
#define DCONV 4
#define DINNER 4096
#define NTOK (BB*TT)              // 4096 tokens

typedef __bf16 bf16x8 __attribute__((ext_vector_type(8)));
typedef float floatx4 __attribute__((ext_vector_type(4)));
typedef unsigned short ushort8v __attribute__((ext_vector_type(8)));
typedef unsigned short ushort4v __attribute__((ext_vector_type(4)));

__device__ __forceinline__ float bf2f(unsigned short u) {
    return __uint_as_float(((unsigned)u) << 16);
}
__device__ __forceinline__ unsigned short f2bf(float f) {
    unsigned u = __float_as_uint(f);
    unsigned r = u + 0x7FFFu + ((u >> 16) & 1u);   // round-nearest-even
    return (unsigned short)(r >> 16);
}
__device__ __forceinline__ float siluf(float x) { return x / (1.f + __expf(-x)); }
__device__ __forceinline__ float softplusf(float x) {
    return fmaxf(x, 0.f) + log1pf(__expf(-fabsf(x)));
}

__device__ __forceinline__ void gload16(const void* g, void* l) {
    __builtin_amdgcn_global_load_lds(
        (const __attribute__((address_space(1))) void*)g,
        (__attribute__((address_space(3))) void*)l, 16, 0, 0);
}

#define BARR __builtin_amdgcn_s_barrier()
#define SCHB __builtin_amdgcn_sched_barrier(0)
#define PRIO1 __builtin_amdgcn_s_setprio(1)
#define PRIO0 __builtin_amdgcn_s_setprio(0)

// ---------------- fp32 -> bf16 weight conversion ----------------
__global__ __launch_bounds__(256) void cvt_kernel(const float* __restrict__ s,
                                                  unsigned short* __restrict__ d, int n) {
    int i = (blockIdx.x * blockDim.x + threadIdx.x) * 4;
    if (i < n) {
        float4 v = *(const float4*)(s + i);
        ushort4v o = {f2bf(v.x), f2bf(v.y), f2bf(v.z), f2bf(v.w)};
        *(ushort4v*)(d + i) = o;
    }
}

// ---------------- fp32 -> fp8 e4m3 (scaled) conversion ----------------
__global__ __launch_bounds__(256) void cvt8_kernel(const float* __restrict__ s,
                                                   unsigned char* __restrict__ d,
                                                   float scale) {
    int i = (blockIdx.x * blockDim.x + threadIdx.x) * 8;
    float4 v0 = *(const float4*)(s + i);
    float4 v1 = *(const float4*)(s + i + 4);
    int lo = __builtin_amdgcn_cvt_pk_fp8_f32(v0.x * scale, v0.y * scale, 0, false);
    lo = __builtin_amdgcn_cvt_pk_fp8_f32(v0.z * scale, v0.w * scale, lo, true);
    int hi = __builtin_amdgcn_cvt_pk_fp8_f32(v1.x * scale, v1.y * scale, 0, false);
    hi = __builtin_amdgcn_cvt_pk_fp8_f32(v1.z * scale, v1.w * scale, hi, true);
    int2 o = {lo, hi};
    *(int2*)(d + i) = o;
}

// ---------------- fused (p0+p1+h) + LayerNorm: fp32 in -> h fp32 + xn bf16 ----------------
__global__ __launch_bounds__(256) void ln3_kernel(const float* __restrict__ p0,
                                                  const float* __restrict__ p1,
                                                  const float* __restrict__ hin,
                                                  const float* __restrict__ g,
                                                  const float* __restrict__ b,
                                                  int hasP,
                                                  float* __restrict__ hout,
                                                  unsigned short* __restrict__ out) {
    const int row = blockIdx.x;
    const long rb = (long)row * DMODEL;
    const int base = threadIdx.x * 8;
    float vv[8];
    float4 v0 = *(const float4*)(hin + rb + base);
    float4 v1 = *(const float4*)(hin + rb + base + 4);
    vv[0]=v0.x; vv[1]=v0.y; vv[2]=v0.z; vv[3]=v0.w;
    vv[4]=v1.x; vv[5]=v1.y; vv[6]=v1.z; vv[7]=v1.w;
    if (hasP) {
        float4 a0 = *(const float4*)(p0 + rb + base);
        float4 a1 = *(const float4*)(p0 + rb + base + 4);
        float4 c0 = *(const float4*)(p1 + rb + base);
        float4 c1 = *(const float4*)(p1 + rb + base + 4);
        vv[0]+=a0.x+c0.x; vv[1]+=a0.y+c0.y; vv[2]+=a0.z+c0.z; vv[3]+=a0.w+c0.w;
        vv[4]+=a1.x+c1.x; vv[5]+=a1.y+c1.y; vv[6]+=a1.z+c1.z; vv[7]+=a1.w+c1.w;
        float4 w0 = {vv[0],vv[1],vv[2],vv[3]}, w1 = {vv[4],vv[5],vv[6],vv[7]};
        *(float4*)(hout + rb + base) = w0;
        *(float4*)(hout + rb + base + 4) = w1;
    }
    float s = 0.f, s2 = 0.f;
#pragma unroll
    for (int j = 0; j < 8; j++) { s += vv[j]; s2 += vv[j] * vv[j]; }
#pragma unroll
    for (int off = 32; off >= 1; off >>= 1) {
        s += __shfl_xor(s, off);
        s2 += __shfl_xor(s2, off);
    }
    __shared__ float red[8];
    int wave = threadIdx.x >> 6, lane = threadIdx.x & 63;
    if (lane == 0) { red[wave] = s; red[4 + wave] = s2; }
    __syncthreads();
    s = red[0] + red[1] + red[2] + red[3];
    s2 = red[4] + red[5] + red[6] + red[7];
    float mu = s * (1.f / DMODEL);
    float var = s2 * (1.f / DMODEL) - mu * mu;
    float rs = rsqrtf(var + 1e-5f);
    ushort8v ov;
#pragma unroll
    for (int j = 0; j < 8; j++)
        ov[j] = f2bf((vv[j] - mu) * rs * g[base + j] + b[base + j]);
    *(ushort8v*)&out[rb + base] = ov;
}

// ---------------- final combine: out = p0 + p1 + h ----------------
__global__ __launch_bounds__(256) void combine3_kernel(const float* __restrict__ p0,
                                                       const float* __restrict__ p1,
                                                       const float* __restrict__ h,
                                                       float* __restrict__ out) {
    long i = (long)(blockIdx.x * blockDim.x + threadIdx.x) * 4;
    float4 a = *(const float4*)(p0 + i);
    float4 b = *(const float4*)(p1 + i);
    float4 c = *(const float4*)(h + i);
    float4 o = {a.x+b.x+c.x, a.y+b.y+c.y, a.z+b.z+c.z, a.w+b.w+c.w};
    *(float4*)(out + i) = o;
}

// ============ 256x256 bf16 GEMM, BK=32, 4-buffer LDS, prefetch depth 3 ============
// 512 thr, 8 waves: wm=w>>2 (M 128-band), wn=w&3 (N 64-band); acc[8][4].
// LDS buffer = A 16KB + B 16KB, x4 = 128KB. Per tile: vmcnt(8) [tile t landed,
// t+1/t+2 in flight]; barrier; STAGE(t+3); 12 ds_read_b128; lgkm(4)->MFMA lo;
// lgkm(0)->MFMA hi. Swizzle: stored 16B slot = ((r&1)*4+chunk)^(ldsrow&7), verified.
template <int EPI>
__global__ __launch_bounds__(512, 1) void gemm_sq(const unsigned short* __restrict__ A,
                                                  const unsigned short* __restrict__ B,
                                                  int Kstr, int RY, int KT, int ldc,
                                                  unsigned short* __restrict__ Cbf,
                                                  float* __restrict__ Cf0,
                                                  float* __restrict__ Cf1) {
    __shared__ __align__(16) char lds[4 * 32768];
    const int tid = threadIdx.x;
    const int w = tid >> 6, lane = tid & 63;
    const int wm = w >> 2, wn = w & 3;

    const int xcd = blockIdx.x & 7;
    const int l = blockIdx.x >> 3;
    const int by = xcd * RY + (l % RY);
    const int rest = l / RY;
    int bx = 0, kpart = 0;
    if constexpr (EPI == 3) { bx = rest & 7; kpart = rest >> 3; }
    else { bx = rest; }
    const long rowBase = (long)by * 256;
    const long colBase = (long)bx * 256;
    const long K0b = (long)kpart * KT * 64;

    // frag-read constants
    const int slotRD = ((((lane & 1) << 2) | (lane >> 4)) ^ ((lane >> 1) & 7)) * 16;
    const char* rdA = lds + wm * 8192 + ((lane >> 1) & 7) * 128 + slotRD;
    const char* rdB = lds + 16384 + wn * 4096 + ((lane >> 1) & 7) * 128 + slotRD;

    // staging source (inverse-swizzled global addr, linear LDS dest)
    const int t8 = tid >> 3;
    const int ch3 = (tid & 7) ^ (t8 & 7);
    const int srow = 2 * t8 + (ch3 >> 2);
    const int coff = (ch3 & 3) * 16;
    const size_t Kb2 = (size_t)Kstr * 2;
    const char* pA1 = (const char*)A + (rowBase + srow) * Kb2 + coff + K0b;
    const char* pA2 = (const char*)A + (rowBase + 128 + srow) * Kb2 + coff + K0b;
    const char* pB1 = (const char*)B + (colBase + srow) * Kb2 + coff + K0b;
    const char* pB2 = (const char*)B + (colBase + 128 + srow) * Kb2 + coff + K0b;
    const long wb = (long)w * 1024;

    floatx4 acc[8][4];
#pragma unroll
    for (int m = 0; m < 8; m++)
#pragma unroll
        for (int n = 0; n < 4; n++) acc[m][n] = floatx4{0.f, 0.f, 0.f, 0.f};

#define STG(BUF, OFF) do { \
    gload16(pA1 + (OFF), lds + (BUF)*32768 + wb); \
    gload16(pA2 + (OFF), lds + (BUF)*32768 + 8192 + wb); \
    gload16(pB1 + (OFF), lds + (BUF)*32768 + 16384 + wb); \
    gload16(pB2 + (OFF), lds + (BUF)*32768 + 24576 + wb); } while(0)

    STG(0, 0);
    STG(1, 64);
    STG(2, 128);

    for (int t = 0; t < KT; t++) {
        const long bo = (long)(t & 3) * 32768;
        const int bufS = (t + 3) & 3;
        const size_t off3 = (size_t)((t + 3 < KT) ? (t + 3) : (KT - 1)) * 64;
        asm volatile("s_waitcnt vmcnt(8)");
        BARR;
        STG(bufS, off3);
        bf16x8 bfr[4], af[8];
#pragma unroll
        for (int n = 0; n < 4; n++) bfr[n] = *(const bf16x8*)(rdB + bo + n * 1024);
#pragma unroll
        for (int m = 0; m < 8; m++) af[m] = *(const bf16x8*)(rdA + bo + m * 1024);
        asm volatile("s_waitcnt lgkmcnt(4)"); SCHB;
        PRIO1;
#pragma unroll
        for (int m = 0; m < 4; m++)
#pragma unroll
            for (int n = 0; n < 4; n++)
                acc[m][n] = __builtin_amdgcn_mfma_f32_16x16x32_bf16(bfr[n], af[m], acc[m][n], 0, 0, 0);
        PRIO0;
        asm volatile("s_waitcnt lgkmcnt(0)"); SCHB;
        PRIO1;
#pragma unroll
        for (int m = 4; m < 8; m++)
#pragma unroll
            for (int n = 0; n < 4; n++)
                acc[m][n] = __builtin_amdgcn_mfma_f32_16x16x32_bf16(bfr[n], af[m], acc[m][n], 0, 0, 0);
        PRIO0;
    }
#undef STG

    // epilogue (M-row = lane&15, N-col = (lane>>4)*4 + reg)
    const int lrow = lane & 15, cg = (lane >> 4) * 4;
    if constexpr (EPI == 0) {
#pragma unroll
        for (int mi = 0; mi < 8; mi++)
#pragma unroll
            for (int n = 0; n < 4; n++) {
                long row = rowBase + wm * 128 + mi * 16 + lrow;
                long col = colBase + wn * 64 + n * 16 + cg;
                ushort4v o = {f2bf(acc[mi][n][0]), f2bf(acc[mi][n][1]),
                              f2bf(acc[mi][n][2]), f2bf(acc[mi][n][3])};
                *(ushort4v*)&Cbf[row * ldc + col] = o;
            }
    } else {   // EPI == 3: fp32 K-split partial
        float* op = (kpart == 0) ? Cf0 : Cf1;
#pragma unroll
        for (int mi = 0; mi < 8; mi++)
#pragma unroll
            for (int n = 0; n < 4; n++) {
                long row = rowBase + wm * 128 + mi * 16 + lrow;
                long col = colBase + wn * 64 + n * 16 + cg;
                *(floatx4*)&op[row * ldc + col] = acc[mi][n];
            }
    }
}

// ============ 256x256 fp8 W_dt GEMM, BK=64 bytes, 4-buffer, prefetch 3 ============
__global__ __launch_bounds__(512, 1) void gemm_dt8(const unsigned char* __restrict__ A8,
                                                   const unsigned char* __restrict__ B8,
                                                   const float* __restrict__ bias,
                                                   float* __restrict__ dmean) {
    __shared__ __align__(16) char lds[4 * 32768];
    const int tid = threadIdx.x;
    const int w = tid >> 6, lane = tid & 63;
    const int wm = w >> 2, wn = w & 3;

    const int xcd = blockIdx.x & 7;
    const int l = blockIdx.x >> 3;
    const int by = xcd * 2 + (l & 1);
    const int bx = l >> 1;             // 0..15
    const long rowBase = (long)by * 256;
    const long colBase = (long)bx * 256;

    int cbs[2];
#pragma unroll
    for (int s = 0; s < 2; s++)
        cbs[s] = (((((lane & 1) << 2) | (s * 2 + (lane >> 5))) ^ ((lane >> 1) & 7)) * 16)
                 + ((lane >> 4) & 1) * 8;
    const char* rdA = lds + wm * 8192 + ((lane >> 1) & 7) * 128;
    const char* rdB = lds + 16384 + wn * 4096 + ((lane >> 1) & 7) * 128;

    const int t8 = tid >> 3;
    const int ch3 = (tid & 7) ^ (t8 & 7);
    const int srow = 2 * t8 + (ch3 >> 2);
    const int coff = (ch3 & 3) * 16;
    const char* pA1 = (const char*)A8 + (rowBase + srow) * (size_t)DINNER + coff;
    const char* pA2 = (const char*)A8 + (rowBase + 128 + srow) * (size_t)DINNER + coff;
    const char* pB1 = (const char*)B8 + (colBase + srow) * (size_t)DINNER + coff;
    const char* pB2 = (const char*)B8 + (colBase + 128 + srow) * (size_t)DINNER + coff;
    const long wb = (long)w * 1024;

    floatx4 acc[8][4];
#pragma unroll
    for (int m = 0; m < 8; m++)
#pragma unroll
        for (int n = 0; n < 4; n++) acc[m][n] = floatx4{0.f, 0.f, 0.f, 0.f};

#define STG8(BUF, OFF) do { \
    gload16(pA1 + (OFF), lds + (BUF)*32768 + wb); \
    gload16(pA2 + (OFF), lds + (BUF)*32768 + 8192 + wb); \
    gload16(pB1 + (OFF), lds + (BUF)*32768 + 16384 + wb); \
    gload16(pB2 + (OFF), lds + (BUF)*32768 + 24576 + wb); } while(0)

    STG8(0, 0);
    STG8(1, 64);
    STG8(2, 128);

    const int KT = DINNER / 64;   // 64 tiles
    for (int t = 0; t < KT; t++) {
        const long bo = (long)(t & 3) * 32768;
        const int bufS = (t + 3) & 3;
        const size_t off3 = (size_t)((t + 3 < KT) ? (t + 3) : (KT - 1)) * 64;
        asm volatile("s_waitcnt vmcnt(8)");
        BARR;
        STG8(bufS, off3);
        long b0[4], a0[8], b1[4], a1[8];
#pragma unroll
        for (int n = 0; n < 4; n++) b0[n] = *(const long*)(rdB + bo + n * 1024 + cbs[0]);
#pragma unroll
        for (int m = 0; m < 8; m++) a0[m] = *(const long*)(rdA + bo + m * 1024 + cbs[0]);
#pragma unroll
        for (int n = 0; n < 4; n++) b1[n] = *(const long*)(rdB + bo + n * 1024 + cbs[1]);
#pragma unroll
        for (int m = 0; m < 8; m++) a1[m] = *(const long*)(rdA + bo + m * 1024 + cbs[1]);
        asm volatile("s_waitcnt lgkmcnt(12)"); SCHB;
        PRIO1;
#pragma unroll
        for (int m = 0; m < 8; m++)
#pragma unroll
            for (int n = 0; n < 4; n++)
                acc[m][n] = __builtin_amdgcn_mfma_f32_16x16x32_fp8_fp8(b0[n], a0[m], acc[m][n], 0, 0, 0);
        PRIO0;
        asm volatile("s_waitcnt lgkmcnt(0)"); SCHB;
        PRIO1;
#pragma unroll
        for (int m = 0; m < 8; m++)
#pragma unroll
            for (int n = 0; n < 4; n++)
                acc[m][n] = __builtin_amdgcn_mfma_f32_16x16x32_fp8_fp8(b1[n], a1[m], acc[m][n], 0, 0, 0);
        PRIO0;
    }
#undef STG8

    // epilogue: softplus(acc/256 + b_dt) row-sum -> dmean atomics
    const int lrow = lane & 15, cg = (lane >> 4) * 4;
    const float SC = 1.f / 256.f;
    float4 bi[4];
#pragma unroll
    for (int n = 0; n < 4; n++)
        bi[n] = *(const float4*)&bias[colBase + wn * 64 + n * 16 + cg];
#pragma unroll
    for (int mi = 0; mi < 8; mi++) {
        float s = 0.f;
#pragma unroll
        for (int n = 0; n < 4; n++) {
            s += softplusf(acc[mi][n][0] * SC + bi[n].x);
            s += softplusf(acc[mi][n][1] * SC + bi[n].y);
            s += softplusf(acc[mi][n][2] * SC + bi[n].z);
            s += softplusf(acc[mi][n][3] * SC + bi[n].w);
        }
        s += __shfl_xor(s, 16);
        s += __shfl_xor(s, 32);
        if ((lane >> 4) == 0)
            atomicAdd(&dmean[rowBase + wm * 128 + mi * 16 + lrow], s);
    }
}

// ============ 128x256 bf16 W_xp GEMM (K-split x8 -> bcp), 3-buffer ============
#define BUFSZ 49152
__global__ __launch_bounds__(512, 1) void gemm_xp(const unsigned short* __restrict__ A,
                                                  const unsigned short* __restrict__ B,
                                                  float* __restrict__ bcout) {
    __shared__ __align__(16) char lds[3 * BUFSZ];
    const int tid = threadIdx.x;
    const int w = tid >> 6, lane = tid & 63;
    const int wm = w >> 2, wn = w & 3;
    const int lrow = lane & 15;

    const int xcd = blockIdx.x & 7;
    const int l = blockIdx.x >> 3;
    const int by = xcd * 4 + (l % 4);
    const int kpart = l / 4;           // 0..7
    const long rowBase = (long)by * 128;
    const long K0b = (long)kpart * 8 * 128;

    const int cb0 = (((lane >> 4))     ^ (lane & 7)) * 16;
    const int cb1 = (((lane >> 4) | 4) ^ (lane & 7)) * 16;
    const char* rdA = lds + (wm * 64 + lrow) * 128;
    const char* rdB = lds + 16384 + (wn * 64 + lrow) * 128;

    const int rsub = lane >> 3;
    const int csrc = (lane & 7) ^ (lane >> 3);
    char* ldsw = lds + w * 1024;
    const size_t Kb = (size_t)DINNER;
    const char* pA[2];
#pragma unroll
    for (int u = 0; u < 2; u++)
        pA[u] = (const char*)(A + (rowBase + u * 64 + w * 8 + rsub) * Kb) + csrc * 16 + K0b;
    const char* pB[4];
#pragma unroll
    for (int u = 0; u < 4; u++)
        pB[u] = (const char*)(B + ((long)u * 64 + w * 8 + rsub) * Kb) + csrc * 16 + K0b;

    floatx4 acc[4][4];
#pragma unroll
    for (int m = 0; m < 4; m++)
#pragma unroll
        for (int n = 0; n < 4; n++) acc[m][n] = floatx4{0.f, 0.f, 0.f, 0.f};
    bf16x8 af0[4], af1[4], bf0[4], bf1[4];

#define STGX(BUF, OFF) do { \
    _Pragma("unroll") for (int u_ = 0; u_ < 2; u_++) \
        gload16(pA[u_] + (OFF), ldsw + (BUF)*BUFSZ + u_*8192); \
    _Pragma("unroll") for (int u_ = 0; u_ < 4; u_++) \
        gload16(pB[u_] + (OFF), ldsw + (BUF)*BUFSZ + 16384 + u_*8192); } while(0)

#define MFMAX(AF, BF) do { _Pragma("unroll") \
  for (int m_ = 0; m_ < 4; m_++) { _Pragma("unroll") \
    for (int n_ = 0; n_ < 4; n_++) \
      acc[m_][n_] = __builtin_amdgcn_mfma_f32_16x16x32_bf16(BF[n_], AF[m_], acc[m_][n_], 0,0,0); } } while(0)

    STGX(0, 0);
    STGX(1, 128);

    const int KT = 8;
    for (int t = 0; t < KT; t++) {
        const int buf = t % 3;
        const int bufS = (t + 2) % 3;
        const long bufOff = (long)buf * BUFSZ;
        const size_t off2 = (size_t)((t + 2 < KT) ? (t + 2) : (KT - 1)) * 128;
        asm volatile("s_waitcnt vmcnt(6)");
        BARR;
        STGX(bufS, off2);
#pragma unroll
        for (int m_ = 0; m_ < 4; m_++)
            af0[m_] = *(const bf16x8*)(rdA + bufOff + m_ * 2048 + cb0);
#pragma unroll
        for (int n_ = 0; n_ < 4; n_++)
            bf0[n_] = *(const bf16x8*)(rdB + bufOff + n_ * 2048 + cb0);
#pragma unroll
        for (int m_ = 0; m_ < 4; m_++)
            af1[m_] = *(const bf16x8*)(rdA + bufOff + m_ * 2048 + cb1);
#pragma unroll
        for (int n_ = 0; n_ < 4; n_++)
            bf1[n_] = *(const bf16x8*)(rdB + bufOff + n_ * 2048 + cb1);
        asm volatile("s_waitcnt lgkmcnt(8)"); SCHB;
        PRIO1; MFMAX(af0, bf0); PRIO0;
        asm volatile("s_waitcnt lgkmcnt(0)"); SCHB;
        PRIO1; MFMAX(af1, bf1); PRIO0;
    }
#undef STGX
#undef MFMAX

    const int cg = (lane >> 4) * 4;
    float* op = bcout + (long)kpart * NTOK * 256;
#pragma unroll
    for (int mi = 0; mi < 4; mi++)
#pragma unroll
        for (int n = 0; n < 4; n++) {
            long row = rowBase + wm * 64 + mi * 16 + lrow;
            long col = wn * 64 + n * 16 + cg;
            *(floatx4*)&op[row * 256 + col] = acc[mi][n];
        }
}

// ---------------- causal depthwise conv1d + bias + silu (bf16 + scaled fp8 out) ----------------
__global__ __launch_bounds__(256) void conv_silu_kernel(const unsigned short* __restrict__ xr,
                                                        const float* __restrict__ w,
                                                        const float* __restrict__ cb,
                                                        unsigned short* __restrict__ xc,
                                                        unsigned char* __restrict__ xc8) {
    int idx = blockIdx.x * blockDim.x + threadIdx.x;   // NTOK * 512
    int d0 = (idx & 511) * 8;
    int bt = idx >> 9;
    int t = bt & (TT - 1);
    float acc[8];
#pragma unroll
    for (int j = 0; j < 8; j++) acc[j] = cb[d0 + j];
#pragma unroll
    for (int k = 0; k < DCONV; k++) {
        int ts = t - (DCONV - 1) + k;
        if (ts < 0) continue;
        ushort8v v = *(const ushort8v*)&xr[(long)(bt - (DCONV - 1) + k) * (2 * DINNER) + d0];
#pragma unroll
        for (int j = 0; j < 8; j++) acc[j] += bf2f(v[j]) * w[(d0 + j) * DCONV + k];
    }
    float sv[8];
    ushort8v ov;
#pragma unroll
    for (int j = 0; j < 8; j++) { sv[j] = siluf(acc[j]); ov[j] = f2bf(sv[j]); }
    *(ushort8v*)&xc[(long)bt * DINNER + d0] = ov;
    int lo = __builtin_amdgcn_cvt_pk_fp8_f32(sv[0] * 4.f, sv[1] * 4.f, 0, false);
    lo = __builtin_amdgcn_cvt_pk_fp8_f32(sv[2] * 4.f, sv[3] * 4.f, lo, true);
    int hi = __builtin_amdgcn_cvt_pk_fp8_f32(sv[4] * 4.f, sv[5] * 4.f, 0, false);
    hi = __builtin_amdgcn_cvt_pk_fp8_f32(sv[6] * 4.f, sv[7] * 4.f, hi, true);
    int2 o8 = {lo, hi};
    *(int2*)&xc8[(long)bt * DINNER + d0] = o8;
}

// ---------------- bc = sum of 8 K-split partials ----------------
__global__ __launch_bounds__(256) void bcsum_kernel(const float* __restrict__ bcp,
                                                    float* __restrict__ bc) {
    long i = (long)(blockIdx.x * blockDim.x + threadIdx.x) * 4;
    const long S = (long)NTOK * 256;
    float4 o = *(const float4*)(bcp + i);
#pragma unroll
    for (int p = 1; p < 8; p++) {
        float4 v = *(const float4*)(bcp + (long)p * S + i);
        o.x += v.x; o.y += v.y; o.z += v.z; o.w += v.w;
    }
    *(float4*)(bc + i) = o;
}

// ---------------- sequential selective-scan, 4-step batched reduction ----------------
__global__ void scan_kernel(const float* __restrict__ dmean, const float* __restrict__ bcmat,
                            const float* __restrict__ A_log, float* __restrict__ ys) {
    int b = blockIdx.x, lane = threadIdx.x;   // 64 lanes, 2 states each
    float A0 = -expf(A_log[lane]);
    float A1 = -expf(A_log[lane + 64]);
    float h0 = 0.f, h1 = 0.f;
    const float inv = 1.f / (float)DINNER;
    const float* rowp = bcmat + (long)b * TT * (2 * DSTATE);
    const float* dmp = dmean + b * TT;
    float B0 = rowp[lane], B1 = rowp[64 + lane];
    float C0 = rowp[128 + lane], C1 = rowp[192 + lane];
    float DM = dmp[0];
    for (int t0 = 0; t0 < TT; t0 += 4) {
        float vv0, vv1, vv2, vv3;
#define STEP(J, VV) do { \
        int t_ = t0 + (J); \
        float nB0 = 0.f, nB1 = 0.f, nC0 = 0.f, nC1 = 0.f, nDM = 0.f; \
        if (t_ + 1 < TT) { \
            const float* nx = rowp + (long)(t_ + 1) * 256; \
            nB0 = nx[lane]; nB1 = nx[64 + lane]; \
            nC0 = nx[128 + lane]; nC1 = nx[192 + lane]; \
            nDM = dmp[t_ + 1]; \
        } \
        float dm = DM * inv; \
        h0 = h0 * __expf(dm * A0) + B0; \
        h1 = h1 * __expf(dm * A1) + B1; \
        VV = h0 * C0 + h1 * C1; \
        B0 = nB0; B1 = nB1; C0 = nC0; C1 = nC1; DM = nDM; } while (0)
        STEP(0, vv0); STEP(1, vv1); STEP(2, vv2); STEP(3, vv3);
#undef STEP
#pragma unroll
        for (int off = 32; off >= 1; off >>= 1) {
            vv0 += __shfl_xor(vv0, off);
            vv1 += __shfl_xor(vv1, off);
            vv2 += __shfl_xor(vv2, off);
            vv3 += __shfl_xor(vv3, off);
        }
        if (lane == 0) {
            float4 o = {vv0, vv1, vv2, vv3};
            *(float4*)&ys[b * TT + t0] = o;
        }
    }
}

// ---------------- y = (ys + D_skip*xc) * silu(res) ----------------
__global__ __launch_bounds__(256) void ycomb_kernel(const float* __restrict__ ys,
                                                    const unsigned short* __restrict__ xc,
                                                    const unsigned short* __restrict__ xr,
                                                    const float* __restrict__ dskip,
                                                    unsigned short* __restrict__ yc) {
    int idx = blockIdx.x * blockDim.x + threadIdx.x;
    int d0 = (idx & 511) * 8;
    int bt = idx >> 9;
    float y = ys[bt];
    ushort8v xcv = *(const ushort8v*)&xc[(long)bt * DINNER + d0];
    ushort8v rv = *(const ushort8v*)&xr[(long)bt * (2 * DINNER) + DINNER + d0];
    ushort8v ov;
#pragma unroll
    for (int j = 0; j < 8; j++) {
        float val = (y + dskip[d0 + j] * bf2f(xcv[j])) * siluf(bf2f(rv[j]));
        ov[j] = f2bf(val);
    }
    *(ushort8v*)&yc[(long)bt * DINNER + d0] = ov;
}

extern "C" void kernel_launch(void* const* d_in, const int* in_sizes, int n_in,
                              void* d_out, int out_size, void* d_ws, size_t ws_size,
                              hipStream_t stream) {
    const float* x      = (const float*)d_in[0];
    const float* ln_g   = (const float*)d_in[1];
    const float* ln_b   = (const float*)d_in[2];
    const float* W_in   = (const float*)d_in[3];
    const float* conv_w = (const float*)d_in[4];
    const float* conv_b = (const float*)d_in[5];
    const float* W_xp   = (const float*)d_in[6];
    const float* W_dt   = (const float*)d_in[7];
    const float* b_dt   = (const float*)d_in[8];
    const float* A_log  = (const float*)d_in[9];
    const float* D_skip = (const float*)d_in[10];
    const float* W_out  = (const float*)d_in[11];
    float* out = (float*)d_out;

    // workspace carve
    char* ws = (char*)d_ws;
    const size_t nWin  = (size_t)2 * DINNER * DMODEL;
    const size_t nWdt  = (size_t)DINNER * DINNER;
    const size_t nWxp  = (size_t)2 * DSTATE * DINNER;
    const size_t nWout = (size_t)DMODEL * DINNER;

    unsigned short* wb_in  = (unsigned short*)ws; ws += nWin * 2;
    unsigned char*  wb_dt8 = (unsigned char*)ws;  ws += nWdt;
    unsigned short* wb_xp  = (unsigned short*)ws; ws += nWxp * 2;
    unsigned short* wb_out = (unsigned short*)ws; ws += nWout * 2;
    unsigned short* xn = (unsigned short*)ws; ws += (size_t)NTOK * DMODEL * 2;
    unsigned short* xr = (unsigned short*)ws; ws += (size_t)NTOK * 2 * DINNER * 2;
    unsigned short* xc = (unsigned short*)ws; ws += (size_t)NTOK * DINNER * 2;
    unsigned char*  xc8 = (unsigned char*)ws; ws += (size_t)NTOK * DINNER;
    unsigned short* yc = (unsigned short*)ws; ws += (size_t)NTOK * DINNER * 2;
    float* bc    = (float*)ws; ws += (size_t)NTOK * 2 * DSTATE * 4;
    float* bcp   = (float*)ws; ws += (size_t)8 * NTOK * 2 * DSTATE * 4;
    float* dmean = (float*)ws; ws += (size_t)NTOK * 4;
    float* ysb   = (float*)ws; ws += (size_t)NTOK * 4;
    float* h0    = (float*)ws; ws += (size_t)NTOK * DMODEL * 4;
    float* h1    = (float*)ws; ws += (size_t)NTOK * DMODEL * 4;
    float* p0    = (float*)ws; ws += (size_t)NTOK * DMODEL * 4;
    float* p1    = (float*)ws; ws += (size_t)NTOK * DMODEL * 4;

    const float* hprev = x;
    for (int lay = 0; lay < NLAYERS; lay++) {
        cvt_kernel<<<(int)(nWin / 1024), 256, 0, stream>>>(W_in + (size_t)lay * nWin, wb_in, (int)nWin);
        cvt8_kernel<<<(int)(nWdt / 2048), 256, 0, stream>>>(W_dt + (size_t)lay * nWdt, wb_dt8, 64.f);
        cvt_kernel<<<(int)(nWxp / 1024), 256, 0, stream>>>(W_xp + (size_t)lay * nWxp, wb_xp, (int)nWxp);
        cvt_kernel<<<(int)(nWout / 1024), 256, 0, stream>>>(W_out + (size_t)lay * nWout, wb_out, (int)nWout);

        hipMemsetAsync(dmean, 0, (size_t)NTOK * 4, stream);

        // 1) fused residual-combine + LayerNorm (layer 0: plain LN on x)
        float* hcur = (lay & 1) ? h1 : h0;
        ln3_kernel<<<NTOK, 256, 0, stream>>>(p0, p1, hprev,
                                             ln_g + lay * DMODEL, ln_b + lay * DMODEL,
                                             lay > 0 ? 1 : 0, hcur, xn);
        if (lay > 0) hprev = hcur;

        // 2) x_and_res = xn @ W_in^T  [4096 x 8192], K=2048, 256² tile: grid 16y x 32x = 512
        gemm_sq<0><<<512, 512, 0, stream>>>(xn, wb_in, DMODEL, 2, 64, 2 * DINNER,
                                            xr, nullptr, nullptr);

        // 3) causal depthwise conv + silu (bf16 + fp8 outputs)
        conv_silu_kernel<<<NTOK * 512 / 256, 256, 0, stream>>>(
            xr, conv_w + (size_t)lay * DINNER * DCONV, conv_b + (size_t)lay * DINNER, xc, xc8);

        // 4a) W_dt fp8 GEMM [4096 x 4096], K=4096, 256² tile: grid 16y x 16x = 256
        gemm_dt8<<<256, 512, 0, stream>>>(xc8, wb_dt8, b_dt + (size_t)lay * DINNER, dmean);

        // 4b) W_xp bf16 GEMM [4096 x 256], K-split x8 (KT=8): grid 32y x 8k = 256
        gemm_xp<<<256, 512, 0, stream>>>(xc, wb_xp, bcp);

        // 4c) bc = sum of partials
        bcsum_kernel<<<(NTOK * 256 / 4) / 256, 256, 0, stream>>>(bcp, bc);

        // 5) sequential scan -> ys
        scan_kernel<<<BB, 64, 0, stream>>>(dmean, bc, A_log + (size_t)lay * DSTATE, ysb);

        // 6) y = (ys + D_skip*xc) * silu(res)
        ycomb_kernel<<<NTOK * 512 / 256, 256, 0, stream>>>(
            ysb, xc, xr, D_skip + (size_t)lay * DINNER, yc);

        // 7) W_out partials [4096 x 2048], K-split x2 (KT=64), 256² tile: grid 16y x 8x x 2k = 256
        gemm_sq<3><<<256, 512, 0, stream>>>(yc, wb_out, DINNER, 2, 64, DMODEL,
                                            nullptr, p0, p1);
    }

    // final: out = p0 + p1 + h5
    combine3_kernel<<<(NTOK * DMODEL / 4) / 256, 256, 0, stream>>>(p0, p1, hprev, out);

    (void)in_sizes; (void)n_in; (void)out_size; (void)ws_size;
}